// Round 1
// baseline (68.317 us; speedup 1.0000x reference)
//
#include <hip/hip_runtime.h>

#define Bn 4
#define Sn 512
#define Hn 128
#define ST 4   // s-rows per block in the fused attention kernel

__device__ __forceinline__ float fast_exp2(float x) { return __builtin_amdgcn_exp2f(x); }
__device__ __forceinline__ float fast_rcp(float x)  { return __builtin_amdgcn_rcpf(x); }

// Kernel 1: q_proj = query @ Wq^T + b ; k_proj = key @ Wk^T, stored TRANSPOSED
// qp  [B*S][H]   row-major
// kpT [B][H][S]  (so score loop reads kpT[h][t] coalesced over t)
__global__ __launch_bounds__(256) void proj_kernel(
    const float* __restrict__ query, const float* __restrict__ key,
    const float* __restrict__ attn_W, const float* __restrict__ attn_b,
    float* __restrict__ qp, float* __restrict__ kpT)
{
    __shared__ float rows[2][8][Hn];
    const int row0 = blockIdx.x * 8;       // global (b*S+s) row
    const int b    = row0 / Sn;
    const int t0   = row0 % Sn;
    const int tid  = threadIdx.x;

    for (int i = tid; i < 8 * Hn; i += 256) {
        int r = i >> 7, c = i & 127;
        rows[0][r][c] = query[(row0 + r) * Hn + c];
        rows[1][r][c] = key  [(row0 + r) * Hn + c];
    }
    __syncthreads();

    const int o     = tid & 127;
    const int which = tid >> 7;            // 0 = q-proj, 1 = k-proj (wave-uniform)
    float acc[8] = {0,0,0,0,0,0,0,0};
    const float* wrow = attn_W + o * (2 * Hn) + which * Hn;  // attn_W[o][which*H + c]
    for (int c = 0; c < Hn; c += 4) {
        float4 wv = *reinterpret_cast<const float4*>(wrow + c);
        #pragma unroll
        for (int r = 0; r < 8; r++) {
            acc[r] += rows[which][r][c+0] * wv.x + rows[which][r][c+1] * wv.y
                    + rows[which][r][c+2] * wv.z + rows[which][r][c+3] * wv.w;
        }
    }
    if (which == 0) {
        float bias = attn_b[o];
        #pragma unroll
        for (int r = 0; r < 8; r++) qp[(row0 + r) * Hn + o] = acc[r] + bias;
    } else {
        #pragma unroll
        for (int r = 0; r < 8; r++) kpT[(b * Hn + o) * Sn + t0 + r] = acc[r];
    }
}

// Kernel 2: fused scores (tanh) -> softmax -> PV, per (b, 4-row s-tile)
__global__ __launch_bounds__(256) void attn_kernel(
    const float* __restrict__ qp, const float* __restrict__ kpT,
    const float* __restrict__ value, const float* __restrict__ v_w,
    float* __restrict__ out, float* __restrict__ out_w)
{
    __shared__ float qs[ST][Hn];
    __shared__ float sc[ST][Sn];
    __shared__ float vw[Hn];
    const int b   = blockIdx.y;
    const int s0  = blockIdx.x * ST;
    const int tid = threadIdx.x;

    for (int i = tid; i < ST * Hn; i += 256)
        qs[i >> 7][i & 127] = qp[(b * Sn + s0 + (i >> 7)) * Hn + (i & 127)];
    if (tid < Hn) vw[tid] = v_w[tid];
    __syncthreads();

    // scores'[s][t] = sum_h vw[h] * rcp(exp2(2*log2e*(q+k)) + 1)
    // true logits = const - 2*scores'  -> softmax is shift-invariant, use -2*scores'
    const float c2 = 2.8853900817779268f;  // 2*log2(e)
    float a0[ST] = {0,0,0,0}, a1[ST] = {0,0,0,0};
    const float* kb = kpT + b * Hn * Sn;
    for (int h = 0; h < Hn; h++) {
        float k0 = kb[h * Sn + tid];         // coalesced over t
        float k1 = kb[h * Sn + tid + 256];
        float w  = vw[h];
        #pragma unroll
        for (int s = 0; s < ST; s++) {
            float q  = qs[s][h];             // LDS broadcast
            float r0 = fast_rcp(fast_exp2((q + k0) * c2) + 1.0f);
            float r1 = fast_rcp(fast_exp2((q + k1) * c2) + 1.0f);
            a0[s] += w * r0;
            a1[s] += w * r1;
        }
    }
    #pragma unroll
    for (int s = 0; s < ST; s++) {
        sc[s][tid]       = -2.0f * a0[s];
        sc[s][tid + 256] = -2.0f * a1[s];
    }
    __syncthreads();

    // softmax: one wave per s-row
    const int wave = tid >> 6, lane = tid & 63;
    {
        const int sr = wave;
        float v[8]; float m = -1e30f;
        #pragma unroll
        for (int i = 0; i < 8; i++) { v[i] = sc[sr][lane + i * 64]; m = fmaxf(m, v[i]); }
        #pragma unroll
        for (int off = 32; off; off >>= 1) m = fmaxf(m, __shfl_xor(m, off, 64));
        float sum = 0.f;
        const float l2e = 1.4426950408889634f;
        #pragma unroll
        for (int i = 0; i < 8; i++) { v[i] = fast_exp2((v[i] - m) * l2e); sum += v[i]; }
        #pragma unroll
        for (int off = 32; off; off >>= 1) sum += __shfl_xor(sum, off, 64);
        float inv = 1.0f / sum;
        float* wrow_out = out_w + (size_t)(b * Sn + s0 + sr) * Sn;
        #pragma unroll
        for (int i = 0; i < 8; i++) {
            float wgt = v[i] * inv;
            sc[sr][lane + i * 64] = wgt;     // keep normalized weights for PV
            wrow_out[lane + i * 64] = wgt;   // coalesced global write
        }
    }
    __syncthreads();

    // PV: out[s][h] = sum_t w[s][t] * value[b][t][h]
    const int h = tid & 127, sg = tid >> 7;  // sg in {0,1} -> rows sg*2, sg*2+1
    float av0 = 0.f, av1 = 0.f;
    const float* vb = value + b * Sn * Hn;
    #pragma unroll 4
    for (int t = 0; t < Sn; t++) {
        float vv = vb[t * Hn + h];           // coalesced
        av0 += sc[sg * 2 + 0][t] * vv;       // LDS broadcast
        av1 += sc[sg * 2 + 1][t] * vv;
    }
    out[(b * Sn + s0 + sg * 2 + 0) * Hn + h] = av0;
    out[(b * Sn + s0 + sg * 2 + 1) * Hn + h] = av1;
}

extern "C" void kernel_launch(void* const* d_in, const int* in_sizes, int n_in,
                              void* d_out, int out_size, void* d_ws, size_t ws_size,
                              hipStream_t stream) {
    const float* query  = (const float*)d_in[0];
    const float* key    = (const float*)d_in[1];
    const float* value  = (const float*)d_in[2];
    const float* attn_W = (const float*)d_in[3];
    const float* attn_b = (const float*)d_in[4];
    const float* v_w    = (const float*)d_in[5];

    float* out   = (float*)d_out;            // (B,S,H) then (B,S,S), both f32
    float* out_w = out + Bn * Sn * Hn;

    float* qp  = (float*)d_ws;               // B*S*H floats = 1 MB
    float* kpT = qp + Bn * Sn * Hn;          // B*H*S floats = 1 MB

    proj_kernel<<<Bn * Sn / 8, 256, 0, stream>>>(query, key, attn_W, attn_b, qp, kpT);
    attn_kernel<<<dim3(Sn / ST, Bn), 256, 0, stream>>>(qp, kpT, value, v_w, out, out_w);
}

// Round 2
// 50.567 us; speedup vs baseline: 1.3510x; 1.3510x over previous
//
#include <hip/hip_runtime.h>

#define Bn 4
#define Sn 512
#define Hn 128
#define ST 4   // s-rows per attention block

__device__ __forceinline__ float fast_exp2(float x) { return __builtin_amdgcn_exp2f(x); }
__device__ __forceinline__ float fast_rcp(float x)  { return __builtin_amdgcn_rcpf(x); }

#define C2 2.8853900817779268f   // 2*log2(e)

// Kernel 1: eq[b][s][h] = exp2(C2*(q@Wq^T + bias)) ; ekT[b][h][t] = exp2(C2*(k@Wk^T))
// 4 rows per block, 512 blocks total.
__global__ __launch_bounds__(256) void proj_kernel(
    const float* __restrict__ query, const float* __restrict__ key,
    const float* __restrict__ attn_W, const float* __restrict__ attn_b,
    float* __restrict__ eq, float* __restrict__ ekT)
{
    __shared__ float rows[2][4][Hn];
    const int row0 = blockIdx.x * 4;       // global (b*S+s) row
    const int b    = row0 / Sn;
    const int t0   = row0 % Sn;            // multiple of 4
    const int tid  = threadIdx.x;

    for (int i = tid; i < 2 * 4 * Hn; i += 256) {
        int src = i >> 9, r = (i >> 7) & 3, c = i & 127;
        rows[src][r][c] = (src == 0 ? query : key)[(row0 + r) * Hn + c];
    }
    __syncthreads();

    const int o     = tid & 127;
    const int which = tid >> 7;            // 0 = q-proj, 1 = k-proj (wave-uniform)
    float acc[4] = {0,0,0,0};
    const float* wrow = attn_W + o * (2 * Hn) + which * Hn;
    for (int c = 0; c < Hn; c += 4) {
        float4 wv = *reinterpret_cast<const float4*>(wrow + c);
        #pragma unroll
        for (int r = 0; r < 4; r++) {
            acc[r] += rows[which][r][c+0] * wv.x + rows[which][r][c+1] * wv.y
                    + rows[which][r][c+2] * wv.z + rows[which][r][c+3] * wv.w;
        }
    }
    if (which == 0) {
        float bias = attn_b[o];
        #pragma unroll
        for (int r = 0; r < 4; r++)
            eq[(row0 + r) * Hn + o] = fast_exp2(C2 * (acc[r] + bias));
    } else {
        float4 ev;
        ev.x = fast_exp2(C2 * acc[0]); ev.y = fast_exp2(C2 * acc[1]);
        ev.z = fast_exp2(C2 * acc[2]); ev.w = fast_exp2(C2 * acc[3]);
        *reinterpret_cast<float4*>(&ekT[(b * Hn + o) * Sn + t0]) = ev;
    }
}

// Kernel 2: fused scores -> softmax -> PV.  512 threads: thread = one t column.
__global__ __launch_bounds__(512) void attn_kernel(
    const float* __restrict__ eq, const float* __restrict__ ekT,
    const float* __restrict__ value, const float* __restrict__ v_w,
    float* __restrict__ out, float* __restrict__ out_w)
{
    __shared__ float qs[ST][Hn];     // exp2-transformed q rows
    __shared__ float sc[ST][Sn];
    __shared__ float vw2[Hn];        // -2 * v_w
    const int b   = blockIdx.y;
    const int s0  = blockIdx.x * ST;
    const int tid = threadIdx.x;

    qs[tid >> 7][tid & 127] = eq[(b * Sn + s0 + (tid >> 7)) * Hn + (tid & 127)];
    if (tid < Hn) vw2[tid] = -2.0f * v_w[tid];
    __syncthreads();

    // logits'[s][t] = sum_h (-2*vw[h]) * rcp(eq[s][h]*ek[h][t] + 1)   (shift-inv.)
    const int t = tid;
    const float* kb = ekT + (size_t)b * Hn * Sn + t;
    float a[ST] = {0,0,0,0};
    float ek[4];
    #pragma unroll
    for (int j = 0; j < 4; j++) ek[j] = kb[j * Sn];
    for (int h = 0; h < Hn; h += 4) {
        float nk[4];
        if (h + 4 < Hn) {
            #pragma unroll
            for (int j = 0; j < 4; j++) nk[j] = kb[(h + 4 + j) * Sn];
        } else {
            #pragma unroll
            for (int j = 0; j < 4; j++) nk[j] = 0.0f;
        }
        #pragma unroll
        for (int j = 0; j < 4; j++) {
            float w = vw2[h + j];
            #pragma unroll
            for (int s = 0; s < ST; s++)
                a[s] += w * fast_rcp(qs[s][h + j] * ek[j] + 1.0f);
        }
        #pragma unroll
        for (int j = 0; j < 4; j++) ek[j] = nk[j];
    }
    #pragma unroll
    for (int s = 0; s < ST; s++) sc[s][t] = a[s];
    __syncthreads();

    // softmax: waves 0..3, one per s-row
    const int wave = tid >> 6, lane = tid & 63;
    if (wave < ST) {
        const int sr = wave;
        float v[8]; float m = -1e30f;
        #pragma unroll
        for (int i = 0; i < 8; i++) { v[i] = sc[sr][lane + i * 64]; m = fmaxf(m, v[i]); }
        #pragma unroll
        for (int off = 32; off; off >>= 1) m = fmaxf(m, __shfl_xor(m, off, 64));
        float sum = 0.f;
        const float l2e = 1.4426950408889634f;
        #pragma unroll
        for (int i = 0; i < 8; i++) { v[i] = fast_exp2((v[i] - m) * l2e); sum += v[i]; }
        #pragma unroll
        for (int off = 32; off; off >>= 1) sum += __shfl_xor(sum, off, 64);
        float inv = 1.0f / sum;
        float* wrow_out = out_w + (size_t)(b * Sn + s0 + sr) * Sn;
        #pragma unroll
        for (int i = 0; i < 8; i++) {
            float wgt = v[i] * inv;
            sc[sr][lane + i * 64] = wgt;
            wrow_out[lane + i * 64] = wgt;
        }
    }
    __syncthreads();

    // PV: thread (sg, h) accumulates out[s0+sg][h] over all 512 t
    const int h = tid & 127, sg = tid >> 7;
    float acc = 0.f;
    const float* vb = value + (size_t)b * Sn * Hn + h;
    #pragma unroll 8
    for (int tt = 0; tt < Sn; tt++)
        acc += sc[sg][tt] * vb[tt * Hn];
    out[(b * Sn + s0 + sg) * Hn + h] = acc;
}

extern "C" void kernel_launch(void* const* d_in, const int* in_sizes, int n_in,
                              void* d_out, int out_size, void* d_ws, size_t ws_size,
                              hipStream_t stream) {
    const float* query  = (const float*)d_in[0];
    const float* key    = (const float*)d_in[1];
    const float* value  = (const float*)d_in[2];
    const float* attn_W = (const float*)d_in[3];
    const float* attn_b = (const float*)d_in[4];
    const float* v_w    = (const float*)d_in[5];

    float* out   = (float*)d_out;            // (B,S,H) then (B,S,S), both f32
    float* out_w = out + Bn * Sn * Hn;

    float* eq  = (float*)d_ws;               // B*S*H floats = 1 MB
    float* ekT = eq + Bn * Sn * Hn;          // B*H*S floats = 1 MB

    proj_kernel<<<Bn * Sn / 4, 256, 0, stream>>>(query, key, attn_W, attn_b, eq, ekT);
    attn_kernel<<<dim3(Sn / ST, Bn), 512, 0, stream>>>(eq, ekT, value, v_w, out, out_w);
}

// Round 3
// 38.206 us; speedup vs baseline: 1.7881x; 1.3235x over previous
//
#include <hip/hip_runtime.h>

#define Bn 4
#define Sn 512
#define Hn 128
#define ST 4   // s-rows per attention block

__device__ __forceinline__ float fast_exp2(float x) { return __builtin_amdgcn_exp2f(x); }
__device__ __forceinline__ float fast_rcp(float x)  { return __builtin_amdgcn_rcpf(x); }

#define C2 2.8853900817779268f   // 2*log2(e)

// Kernel 1: eq[b][s][h] = exp2(C2*(q@Wq^T + bias)) ; ekT[b][h][t] = exp2(C2*(k@Wk^T))
__global__ __launch_bounds__(256) void proj_kernel(
    const float* __restrict__ query, const float* __restrict__ key,
    const float* __restrict__ attn_W, const float* __restrict__ attn_b,
    float* __restrict__ eq, float* __restrict__ ekT)
{
    __shared__ float rows[2][4][Hn];
    const int row0 = blockIdx.x * 4;       // global (b*S+s) row
    const int b    = row0 / Sn;
    const int t0   = row0 % Sn;            // multiple of 4
    const int tid  = threadIdx.x;

    for (int i = tid; i < 2 * 4 * Hn; i += 256) {
        int src = i >> 9, r = (i >> 7) & 3, c = i & 127;
        rows[src][r][c] = (src == 0 ? query : key)[(row0 + r) * Hn + c];
    }
    __syncthreads();

    const int o     = tid & 127;
    const int which = tid >> 7;            // 0 = q-proj, 1 = k-proj (wave-uniform)
    float acc[4] = {0,0,0,0};
    const float* wrow = attn_W + o * (2 * Hn) + which * Hn;
    for (int c = 0; c < Hn; c += 4) {
        float4 wv = *reinterpret_cast<const float4*>(wrow + c);
        #pragma unroll
        for (int r = 0; r < 4; r++) {
            acc[r] += rows[which][r][c+0] * wv.x + rows[which][r][c+1] * wv.y
                    + rows[which][r][c+2] * wv.z + rows[which][r][c+3] * wv.w;
        }
    }
    if (which == 0) {
        float bias = attn_b[o];
        #pragma unroll
        for (int r = 0; r < 4; r++)
            eq[(row0 + r) * Hn + o] = fast_exp2(C2 * (acc[r] + bias));
    } else {
        float4 ev;
        ev.x = fast_exp2(C2 * acc[0]); ev.y = fast_exp2(C2 * acc[1]);
        ev.z = fast_exp2(C2 * acc[2]); ev.w = fast_exp2(C2 * acc[3]);
        *reinterpret_cast<float4*>(&ekT[(b * Hn + o) * Sn + t0]) = ev;
    }
}

// Kernel 2: fused scores -> softmax -> PV.  512 threads, thread = one t column.
__global__ __launch_bounds__(512) void attn_kernel(
    const float* __restrict__ eq, const float* __restrict__ ekT,
    const float* __restrict__ value, const float* __restrict__ v_w,
    float* __restrict__ out, float* __restrict__ out_w)
{
    __shared__ float4 qs4[Hn];            // qs4[h] = {eq[s0..s0+3][h]}
    __shared__ float4 vw4[Hn / 4];        // -2*v_w, packed
    __shared__ float4 scT4[Sn];           // scT4[t] = scores/weights for s rows 0..3
    __shared__ float4 part4[16][ST][Hn / 4];  // PV partials over 16 t-groups

    const int b   = blockIdx.y;
    const int s0  = blockIdx.x * ST;
    const int tid = threadIdx.x;

    {   // load q rows transposed: qs4[h][s]
        const int s = tid >> 7, h = tid & 127;
        ((float*)&qs4[h])[s] = eq[(b * Sn + s0 + s) * Hn + h];
        if (tid < Hn) ((float*)vw4)[tid] = -2.0f * v_w[tid];
    }
    __syncthreads();

    // ---- score phase: logits'[s][t] = sum_h (-2 v_w[h]) * rcp(eq*ek + 1) ----
    const int t = tid;
    const float* kb = ekT + (size_t)b * Hn * Sn + t;
    float a0 = 0.f, a1 = 0.f, a2 = 0.f, a3 = 0.f;
    float ek[8];
    #pragma unroll
    for (int j = 0; j < 8; j++) ek[j] = kb[j * Sn];
    for (int h = 0; h < Hn; h += 8) {
        float nk[8];
        #pragma unroll
        for (int j = 0; j < 8; j++) nk[j] = (h + 8 < Hn) ? kb[(h + 8 + j) * Sn] : 0.0f;
        float4 wA = vw4[(h >> 2) + 0];
        float4 wB = vw4[(h >> 2) + 1];
        const float wj[8] = {wA.x, wA.y, wA.z, wA.w, wB.x, wB.y, wB.z, wB.w};
        #pragma unroll
        for (int j = 0; j < 8; j++) {
            float4 q4 = qs4[h + j];        // one b128 broadcast
            float w = wj[j];
            a0 += w * fast_rcp(q4.x * ek[j] + 1.0f);
            a1 += w * fast_rcp(q4.y * ek[j] + 1.0f);
            a2 += w * fast_rcp(q4.z * ek[j] + 1.0f);
            a3 += w * fast_rcp(q4.w * ek[j] + 1.0f);
        }
        #pragma unroll
        for (int j = 0; j < 8; j++) ek[j] = nk[j];
    }
    float4 av; av.x = a0; av.y = a1; av.z = a2; av.w = a3;
    scT4[t] = av;                          // one b128 write, conflict-free
    __syncthreads();

    // ---- softmax: waves 0..3, one per s-row ----
    const int wave = tid >> 6, lane = tid & 63;
    if (wave < ST) {
        const int sr = wave;
        float v[8]; float m = -1e30f;
        #pragma unroll
        for (int i = 0; i < 8; i++) {
            v[i] = ((const float*)&scT4[lane + i * 64])[sr];
            m = fmaxf(m, v[i]);
        }
        #pragma unroll
        for (int off = 32; off; off >>= 1) m = fmaxf(m, __shfl_xor(m, off, 64));
        float sum = 0.f;
        const float l2e = 1.4426950408889634f;
        #pragma unroll
        for (int i = 0; i < 8; i++) { v[i] = fast_exp2((v[i] - m) * l2e); sum += v[i]; }
        #pragma unroll
        for (int off = 32; off; off >>= 1) sum += __shfl_xor(sum, off, 64);
        float inv = 1.0f / sum;
        float* wrow_out = out_w + (size_t)(b * Sn + s0 + sr) * Sn;
        #pragma unroll
        for (int i = 0; i < 8; i++) {
            float wgt = v[i] * inv;
            ((float*)&scT4[lane + i * 64])[sr] = wgt;
            wrow_out[lane + i * 64] = wgt;   // coalesced global write
        }
    }
    __syncthreads();

    // ---- PV: t-split. thread = (tg in 16, hq in 32); value read once per block ----
    {
        const int hq = tid & 31, tg = tid >> 5;
        const float* vb = value + ((size_t)b * Sn + tg * 32) * Hn + hq * 4;
        float4 A0 = {0,0,0,0}, A1 = {0,0,0,0}, A2 = {0,0,0,0}, A3 = {0,0,0,0};
        #pragma unroll 4
        for (int i = 0; i < 32; i++) {
            float4 v4 = *reinterpret_cast<const float4*>(vb + i * Hn);
            float4 w4 = scT4[tg * 32 + i];   // b128 broadcast
            A0.x += w4.x * v4.x; A0.y += w4.x * v4.y; A0.z += w4.x * v4.z; A0.w += w4.x * v4.w;
            A1.x += w4.y * v4.x; A1.y += w4.y * v4.y; A1.z += w4.y * v4.z; A1.w += w4.y * v4.w;
            A2.x += w4.z * v4.x; A2.y += w4.z * v4.y; A2.z += w4.z * v4.z; A2.w += w4.z * v4.w;
            A3.x += w4.w * v4.x; A3.y += w4.w * v4.y; A3.z += w4.w * v4.z; A3.w += w4.w * v4.w;
        }
        part4[tg][0][hq] = A0;
        part4[tg][1][hq] = A1;
        part4[tg][2][hq] = A2;
        part4[tg][3][hq] = A3;
    }
    __syncthreads();
    {
        const int sg = tid >> 7, h = tid & 127;
        float r = 0.f;
        #pragma unroll
        for (int tg = 0; tg < 16; tg++)
            r += ((const float*)&part4[tg][sg][h >> 2])[h & 3];
        out[(b * Sn + s0 + sg) * Hn + h] = r;
    }
}

extern "C" void kernel_launch(void* const* d_in, const int* in_sizes, int n_in,
                              void* d_out, int out_size, void* d_ws, size_t ws_size,
                              hipStream_t stream) {
    const float* query  = (const float*)d_in[0];
    const float* key    = (const float*)d_in[1];
    const float* value  = (const float*)d_in[2];
    const float* attn_W = (const float*)d_in[3];
    const float* attn_b = (const float*)d_in[4];
    const float* v_w    = (const float*)d_in[5];

    float* out   = (float*)d_out;            // (B,S,H) then (B,S,S), both f32
    float* out_w = out + Bn * Sn * Hn;

    float* eq  = (float*)d_ws;               // B*S*H floats = 1 MB
    float* ekT = eq + Bn * Sn * Hn;          // B*H*S floats = 1 MB

    proj_kernel<<<Bn * Sn / 4, 256, 0, stream>>>(query, key, attn_W, attn_b, eq, ekT);
    attn_kernel<<<dim3(Sn / ST, Bn), 512, 0, stream>>>(eq, ekT, value, v_w, out, out_w);
}